// Round 12
// baseline (1110.844 us; speedup 1.0000x reference)
//
#include <hip/hip_runtime.h>
#include <hip/hip_bf16.h>

typedef __attribute__((ext_vector_type(8))) short s16x8;
typedef __attribute__((ext_vector_type(4))) short s16x4;
typedef __attribute__((ext_vector_type(4))) float f32x4;

#define T_TOK 4096
#define DMODEL 2048
#define ISH 4096
#define IMOE 2048
#define NEXP 16
#define MAXTILES 80
#define PADMAX (MAXTILES*128)     // 10240
#define WELEM ((size_t)ISH*DMODEL) // elems per shared weight matrix

// ---- workspace layout (bytes) ----
#define XB_OFF   ((size_t)0)                              // 16,777,216
#define H_OFF    ((size_t)16777216)
#define H_BYTES  ((size_t)PADMAX*IMOE*2)                  // 41,943,040 (covers T*ISH too)
#define Y_OFF    (H_OFF + H_BYTES)                        // 58,720,256
#define Y_BYTES  ((size_t)2*T_TOK*DMODEL*2)               // 33,554,432
#define C_OFF    (Y_OFF + Y_BYTES)                        // 92,274,688
#define WSH_OFF  (C_OFF + (size_t)1048576)                // 93,323,264
#define WSH_BYTES ((size_t)3*WELEM*2)                     // 50,331,648
#define WS_NEED  (WSH_OFF + WSH_BYTES)                    // ~143.7 MB
// control block offsets (bytes from C_OFF)
#define CNT_OFF    0
#define OFF_OFF    64
#define CUR_OFF    192
#define TILEE_OFF  256
#define TKI_OFF    1024
#define TKW_OFF    (TKI_OFF + T_TOK*2*4)
#define LCODE_OFF  (TKW_OFF + T_TOK*2*4)
#define LW_OFF     (LCODE_OFF + PADMAX*4)

__device__ __forceinline__ unsigned short f2bf(float f) {
    union { float f; unsigned u; } c; c.f = f;
    unsigned u = c.u;
    u += 0x7fffu + ((u >> 16) & 1u);   // RNE
    return (unsigned short)(u >> 16);
}
__device__ __forceinline__ float bf2f(unsigned short h) {
    union { unsigned u; float f; } c; c.u = ((unsigned)h) << 16; return c.f;
}

__device__ __forceinline__ s16x8 cvt8(float4 a, float4 b) {
    union { __hip_bfloat162 h2[4]; s16x8 v; } u;
    u.h2[0] = __float22bfloat162_rn(make_float2(a.x, a.y));
    u.h2[1] = __float22bfloat162_rn(make_float2(a.z, a.w));
    u.h2[2] = __float22bfloat162_rn(make_float2(b.x, b.y));
    u.h2[3] = __float22bfloat162_rn(make_float2(b.z, b.w));
    return u.v;
}

__device__ __forceinline__ void gl_lds16(const unsigned short* g, unsigned short* l) {
    __builtin_amdgcn_global_load_lds(
        (const __attribute__((address_space(1))) unsigned int*)g,
        (__attribute__((address_space(3))) unsigned int*)l,
        16, 0, 0);
}

// ---- cast x (fp32) -> xb (bf16) ----
__global__ void cvt_x_kernel(const float* __restrict__ x, unsigned short* __restrict__ xb) {
    size_t i = (size_t)blockIdx.x * 256 + threadIdx.x;
    float4 v = ((const float4*)x)[i];
    s16x4 o;
    o[0] = (short)f2bf(v.x); o[1] = (short)f2bf(v.y);
    o[2] = (short)f2bf(v.z); o[3] = (short)f2bf(v.w);
    ((s16x4*)xb)[i] = o;
}

// ---- shared weights fp32 -> bf16 (w1 | w3 | w2 contiguous) ----
__global__ void wcvt_sh_kernel(const float* __restrict__ a, const float* __restrict__ b,
                               const float* __restrict__ c, unsigned short* __restrict__ o) {
    size_t i = (size_t)blockIdx.x * 256 + threadIdx.x;
    size_t w = i >> 20;
    size_t idx = (i & ((((size_t)1) << 20) - 1)) << 3;
    const float* src = (w == 0) ? a : (w == 1) ? b : c;
    float4 x = *(const float4*)(src + idx);
    float4 y = *(const float4*)(src + idx + 4);
    *(s16x8*)(o + (i << 3)) = cvt8(x, y);
}

// ---- gate ----
__global__ void gate_kernel(const float* __restrict__ x, const float* __restrict__ wg,
                            int* __restrict__ tki, float* __restrict__ tkw, int* __restrict__ cnt) {
    int t = blockIdx.x;
    __shared__ float xs[DMODEL];
    __shared__ float lg[NEXP];
    const float* xr = x + (size_t)t * DMODEL;
    for (int i = threadIdx.x; i < DMODEL; i += 256) xs[i] = xr[i];
    __syncthreads();
    int g = threadIdx.x >> 4, l = threadIdx.x & 15;
    const float* w = wg + (size_t)g * DMODEL;
    double s = 0.0;
    for (int i = l; i < DMODEL; i += 16) s += (double)xs[i] * (double)w[i];
    for (int m = 8; m >= 1; m >>= 1) s += __shfl_xor(s, m, 64);
    if (l == 0) lg[g] = (float)s;
    __syncthreads();
    if (threadIdx.x == 0) {
        float v0 = -1e30f, v1 = -1e30f; int i0 = 0, i1 = 0;
        for (int e = 0; e < NEXP; e++) {
            float v = lg[e];
            if (v > v0) { v1 = v0; i1 = i0; v0 = v; i0 = e; }
            else if (v > v1) { v1 = v; i1 = e; }
        }
        float w0 = 1.f / (1.f + expf(v1 - v0));
        float w1 = 1.f - w0;
        tki[t*2] = i0; tki[t*2+1] = i1;
        tkw[t*2] = w0; tkw[t*2+1] = w1;
        atomicAdd(&cnt[i0], 1); atomicAdd(&cnt[i1], 1);
    }
}

// ---- scan: 128-aligned segments ----
__global__ void scan_kernel(const int* __restrict__ cnt, int* __restrict__ off,
                            int* __restrict__ cur, int* __restrict__ tile_e,
                            int* __restrict__ lcode) {
    __shared__ int soff[17];
    if (threadIdx.x == 0) {
        int o = 0;
        for (int e = 0; e < NEXP; e++) {
            soff[e] = o; off[e] = o; cur[e] = 0;
            o += (cnt[e] + 127) & ~127;
        }
        soff[16] = o; off[16] = o;
    }
    __syncthreads();
    int ntiles = soff[16] >> 7;
    for (int i = threadIdx.x; i < MAXTILES; i += 256) {
        int e = -1;
        if (i < ntiles) {
            for (int j = 0; j < NEXP; j++)
                if (i*128 >= soff[j] && i*128 < soff[j+1]) e = j;
        }
        tile_e[i] = e;
    }
    for (int p = threadIdx.x; p < PADMAX; p += 256) lcode[p] = -1;
}

__global__ void fill_kernel(const int* __restrict__ tki, const float* __restrict__ tkw,
                            const int* __restrict__ off, int* __restrict__ cur,
                            int* __restrict__ lcode, float* __restrict__ lw) {
    int t = blockIdx.x * 256 + threadIdx.x;
    if (t >= T_TOK) return;
    for (int k = 0; k < 2; k++) {
        int e = tki[t*2+k];
        int p = atomicAdd(&cur[e], 1);
        int pos = off[e] + p;
        lcode[pos] = t*2 + k;
        lw[pos] = tkw[t*2+k];
    }
}

// ===================================================================
// r8 geometry + full-compute-phase latency cover (plain barriers):
// BM=BN=128, BK=64, 256 thr / 4 waves (2x2), dual acc (gemm1).
// A DOUBLE-buffered via gl_lds: A(t+1) issued after drain barrier,
// flies over compute(t), drained by next top __syncthreads (vmcnt0).
// B register-prefetch one K-tile ahead in the same slot.
// gemm1 fp32 path: B1 prefetched, B3 staged in-phase (reg budget).
// gemm2: full B prefetch + __launch_bounds__(256,3) -> 3 blocks/CU.
// Protocol per tile: (a) sync [drains A(t)+B-prefetch; readers of
// t-1 done] -> write B(t) to LDS -> (b) sync [ds_writes visible] ->
// issue A(t+1) gl_lds + B(t+1) loads -> sched_barrier -> compute(t).
// Swizzle: byte ^= ((row&7)<<4) in 128B rows; conflicts measured 0.
// ===================================================================

// ---- GEMM1: H = silu(A@W1^T) * (A@W3^T) * wt ----
template<bool ROUTED, bool BF16W>
__global__ __launch_bounds__(256, 2)
void gemm1_kernel(const unsigned short* __restrict__ xb,
                  const void* __restrict__ w1v, const void* __restrict__ w3v,
                  unsigned short* __restrict__ H, const int N,
                  const int* __restrict__ list_code, const float* __restrict__ list_w,
                  const int* __restrict__ tile_e) {
    const int K = DMODEL;
    const int NT = K / 64;
    int gx = gridDim.x, gy = gridDim.y;
    int wg0 = blockIdx.y * gx + blockIdx.x;
    int cpx = (gx * gy) >> 3;
    int sw = (wg0 & 7) * cpx + (wg0 >> 3);
    int mt = sw % gy, nt = sw / gy;
    const float *w1 = nullptr, *w3 = nullptr;
    const unsigned short *w1h = nullptr, *w3h = nullptr;
    if constexpr (BF16W) { w1h = (const unsigned short*)w1v; w3h = (const unsigned short*)w3v; }
    else                 { w1  = (const float*)w1v;          w3  = (const float*)w3v; }
    if (ROUTED) {
        int e = tile_e[mt];
        if (e < 0) return;
        size_t es = (size_t)N * K;
        if constexpr (BF16W) { w1h += (size_t)e * es; w3h += (size_t)e * es; }
        else                 { w1  += (size_t)e * es; w3  += (size_t)e * es; }
    }
    int m0 = mt*128, n0 = nt*128;

    __shared__ alignas(16) unsigned short Ab[2][128*64];  // 32 KB (double)
    __shared__ alignas(16) unsigned short B1s[128*64];    // 16 KB
    __shared__ alignas(16) unsigned short B3s[128*64];    // 16 KB
    __shared__ int   toks[128];
    __shared__ float wts[128];

    int tid = threadIdx.x;
    if (tid < 128) {
        if (ROUTED) {
            int code = list_code[m0 + tid];
            toks[tid] = (code < 0) ? 0 : (code >> 1);
            wts[tid]  = (code < 0) ? 0.f : list_w[m0 + tid];
        } else {
            toks[tid] = m0 + tid; wts[tid] = 1.f;
        }
    }
    __syncthreads();

    // A staging: 4 x gl_lds (1024 chunks / 256 thr), pre-swizzled source
    const unsigned short* aSrc[4];
    int aDst[4];
    #pragma unroll
    for (int r = 0; r < 4; r++) {
        int c = r*256 + tid, row = c >> 3;
        int kb = ((c & 7) * 16) ^ ((row & 7) << 4);
        aSrc[r] = xb + (size_t)toks[row] * K + (kb >> 1);
        aDst[r] = c * 8;
    }
    // B staging: 4 chunks/thread per matrix, swizzled ds_write offsets
    const unsigned short *b1h4[4], *b3h4[4];
    const float *b1f[4], *b3f[4];
    int bW[4];
    #pragma unroll
    for (int p = 0; p < 4; p++) {
        int c = p*256 + tid, row = c >> 3, slot = c & 7;
        bW[p] = row*64 + ((slot ^ (row & 7)) << 3);
        if constexpr (BF16W) {
            b1h4[p] = w1h + (size_t)(n0 + row) * K + slot*8;
            b3h4[p] = w3h + (size_t)(n0 + row) * K + slot*8;
        } else {
            b1f[p] = w1 + (size_t)(n0 + row) * K + slot*8;
            b3f[p] = w3 + (size_t)(n0 + row) * K + slot*8;
        }
    }

    int wid = tid >> 6, lane = tid & 63;
    int wr = wid >> 1, wc = wid & 1;
    int l15 = lane & 15, lq = lane >> 4, lx = (lane & 7) << 4;
    int arow = wr*64 + l15, brow = wc*64 + l15;
    int ka0 = ((lq*16) ^ lx) >> 1;
    int ka1 = ((64 + lq*16) ^ lx) >> 1;

    f32x4 acc1[4][4], acc2[4][4];
    #pragma unroll
    for (int a = 0; a < 4; a++)
        #pragma unroll
        for (int b = 0; b < 4; b++) {
            acc1[a][b] = (f32x4){0.f,0.f,0.f,0.f};
            acc2[a][b] = (f32x4){0.f,0.f,0.f,0.f};
        }

    // ---- prologue: B(0) prefetch regs + A(0) gl_lds ----
    s16x8 rb1[4], rb3[4];     // BF16W prefetch
    float4 r1[4][2];          // fp32 path: B1 prefetch only
    if constexpr (BF16W) {
        #pragma unroll
        for (int p = 0; p < 4; p++) { rb1[p] = *(const s16x8*)b1h4[p]; rb3[p] = *(const s16x8*)b3h4[p]; }
    } else {
        #pragma unroll
        for (int p = 0; p < 4; p++) { r1[p][0] = *(const float4*)b1f[p]; r1[p][1] = *(const float4*)(b1f[p] + 4); }
    }
    #pragma unroll
    for (int r = 0; r < 4; r++) gl_lds16(aSrc[r], &Ab[0][aDst[r]]);

    for (int t = 0; t < NT; ++t) {
        int kt = t * 64, kn = kt + 64;
        bool pre = (t + 1 < NT);
        __syncthreads();               // (a): drains A(t) gl_lds + B prefetch; readers of t-1 done
        if constexpr (BF16W) {
            #pragma unroll
            for (int p = 0; p < 4; p++) { *(s16x8*)&B1s[bW[p]] = rb1[p]; *(s16x8*)&B3s[bW[p]] = rb3[p]; }
        } else {
            #pragma unroll
            for (int p = 0; p < 4; p++) *(s16x8*)&B1s[bW[p]] = cvt8(r1[p][0], r1[p][1]);
            #pragma unroll
            for (int p = 0; p < 4; p++) {       // B3 staged in-phase (reg budget)
                float4 a3 = *(const float4*)(b3f[p] + kt);
                float4 b3 = *(const float4*)(b3f[p] + kt + 4);
                *(s16x8*)&B3s[bW[p]] = cvt8(a3, b3);
            }
        }
        __syncthreads();               // (b): ds_writes visible; no vmem outstanding
        if (pre) {
            #pragma unroll
            for (int r = 0; r < 4; r++) gl_lds16(aSrc[r] + kn, &Ab[(t+1)&1][aDst[r]]);
            if constexpr (BF16W) {
                #pragma unroll
                for (int p = 0; p < 4; p++) { rb1[p] = *(const s16x8*)(b1h4[p] + kn); rb3[p] = *(const s16x8*)(b3h4[p] + kn); }
            } else {
                #pragma unroll
                for (int p = 0; p < 4; p++) { r1[p][0] = *(const float4*)(b1f[p] + kn); r1[p][1] = *(const float4*)(b1f[p] + kn + 4); }
            }
        }
        __builtin_amdgcn_sched_barrier(0);   // pin load issue before compute
        // ---- compute tile t from Ab[t&1] ----
        const unsigned short* Ac = &Ab[t & 1][0];
        #pragma unroll
        for (int s = 0; s < 2; s++) {
            int ka = s ? ka1 : ka0;
            s16x8 af[4], b1fr[4], b3fr[4];
            #pragma unroll
            for (int f = 0; f < 4; f++) {
                af[f]   = *(const s16x8*)&Ac [(arow + f*16)*64 + ka];
                b1fr[f] = *(const s16x8*)&B1s[(brow + f*16)*64 + ka];
                b3fr[f] = *(const s16x8*)&B3s[(brow + f*16)*64 + ka];
            }
            __builtin_amdgcn_s_setprio(1);
            #pragma unroll
            for (int mf = 0; mf < 4; mf++)
                #pragma unroll
                for (int nf = 0; nf < 4; nf++) {
                    acc1[mf][nf] = __builtin_amdgcn_mfma_f32_16x16x32_bf16(af[mf], b1fr[nf], acc1[mf][nf], 0,0,0);
                    acc2[mf][nf] = __builtin_amdgcn_mfma_f32_16x16x32_bf16(af[mf], b3fr[nf], acc2[mf][nf], 0,0,0);
                }
            __builtin_amdgcn_s_setprio(0);
        }
    }

    // ---- epilogue ----
    #pragma unroll
    for (int mf = 0; mf < 4; mf++) {
        int ib = wr*64 + mf*16 + lq*4;
        #pragma unroll
        for (int nf = 0; nf < 4; nf++) {
            int j = n0 + wc*64 + nf*16 + l15;
            #pragma unroll
            for (int r = 0; r < 4; r++) {
                int i = ib + r;
                float v1 = acc1[mf][nf][r], v2 = acc2[mf][nf][r];
                float sg = v1 / (1.f + __expf(-v1));
                float h = sg * v2 * wts[i];
                H[(size_t)(m0+i)*N + j] = f2bf(h);
            }
        }
    }
}

// ---- GEMM2: Y = H @ W2^T ----
template<bool ROUTED, bool BF16W>
__global__ __launch_bounds__(256, 3)
void gemm2_kernel(const unsigned short* __restrict__ Hm, const void* __restrict__ w2v,
                  float* __restrict__ out, unsigned short* __restrict__ y, const int K,
                  const int* __restrict__ list_code, const int* __restrict__ tile_e) {
    const int N = DMODEL;
    const int NT = K / 64;
    int gx = gridDim.x, gy = gridDim.y;
    int wg0 = blockIdx.y * gx + blockIdx.x;
    int cpx = (gx * gy) >> 3;
    int sw = (wg0 & 7) * cpx + (wg0 >> 3);
    int mt = sw % gy, nt = sw / gy;
    const float* w2 = nullptr; const unsigned short* w2h = nullptr;
    if constexpr (BF16W) w2h = (const unsigned short*)w2v; else w2 = (const float*)w2v;
    if (ROUTED) {
        int e = tile_e[mt];
        if (e < 0) return;
        if constexpr (BF16W) w2h += (size_t)e * N * K; else w2 += (size_t)e * N * K;
    }
    int m0 = mt*128, n0 = nt*128;

    __shared__ alignas(16) unsigned short Ab[2][128*64];  // 32 KB
    __shared__ alignas(16) unsigned short Bs[128*64];     // 16 KB
    __shared__ int codes[128];
    int tid = threadIdx.x;
    if (ROUTED && tid < 128) codes[tid] = list_code[m0 + tid];
    if (ROUTED) __syncthreads();

    const unsigned short* aSrc[4];
    int aDst[4];
    #pragma unroll
    for (int r = 0; r < 4; r++) {
        int c = r*256 + tid, row = c >> 3;
        int kb = ((c & 7) * 16) ^ ((row & 7) << 4);
        aSrc[r] = Hm + (size_t)(m0 + row) * K + (kb >> 1);
        aDst[r] = c * 8;
    }
    const unsigned short* bh4[4];
    const float* bf[4];
    int bW[4];
    #pragma unroll
    for (int p = 0; p < 4; p++) {
        int c = p*256 + tid, row = c >> 3, slot = c & 7;
        bW[p] = row*64 + ((slot ^ (row & 7)) << 3);
        if constexpr (BF16W) bh4[p] = w2h + (size_t)(n0 + row) * K + slot*8;
        else                 bf[p]  = w2  + (size_t)(n0 + row) * K + slot*8;
    }

    int wid = tid >> 6, lane = tid & 63;
    int wr = wid >> 1, wc = wid & 1;
    int l15 = lane & 15, lq = lane >> 4, lx = (lane & 7) << 4;
    int arow = wr*64 + l15, brow = wc*64 + l15;
    int ka0 = ((lq*16) ^ lx) >> 1;
    int ka1 = ((64 + lq*16) ^ lx) >> 1;

    f32x4 acc[4][4];
    #pragma unroll
    for (int a = 0; a < 4; a++)
        #pragma unroll
        for (int b = 0; b < 4; b++) acc[a][b] = (f32x4){0.f,0.f,0.f,0.f};

    // prologue: B(0) prefetch + A(0) gl_lds
    s16x8 rbh[4];
    float4 rb[4][2];
    if constexpr (BF16W) {
        #pragma unroll
        for (int p = 0; p < 4; p++) rbh[p] = *(const s16x8*)bh4[p];
    } else {
        #pragma unroll
        for (int p = 0; p < 4; p++) { rb[p][0] = *(const float4*)bf[p]; rb[p][1] = *(const float4*)(bf[p] + 4); }
    }
    #pragma unroll
    for (int r = 0; r < 4; r++) gl_lds16(aSrc[r], &Ab[0][aDst[r]]);

    for (int t = 0; t < NT; ++t) {
        int kn = (t + 1) * 64;
        bool pre = (t + 1 < NT);
        __syncthreads();               // (a)
        if constexpr (BF16W) {
            #pragma unroll
            for (int p = 0; p < 4; p++) *(s16x8*)&Bs[bW[p]] = rbh[p];
        } else {
            #pragma unroll
            for (int p = 0; p < 4; p++) *(s16x8*)&Bs[bW[p]] = cvt8(rb[p][0], rb[p][1]);
        }
        __syncthreads();               // (b)
        if (pre) {
            #pragma unroll
            for (int r = 0; r < 4; r++) gl_lds16(aSrc[r] + kn, &Ab[(t+1)&1][aDst[r]]);
            if constexpr (BF16W) {
                #pragma unroll
                for (int p = 0; p < 4; p++) rbh[p] = *(const s16x8*)(bh4[p] + kn);
            } else {
                #pragma unroll
                for (int p = 0; p < 4; p++) { rb[p][0] = *(const float4*)(bf[p] + kn); rb[p][1] = *(const float4*)(bf[p] + kn + 4); }
            }
        }
        __builtin_amdgcn_sched_barrier(0);
        const unsigned short* Ac = &Ab[t & 1][0];
        #pragma unroll
        for (int s = 0; s < 2; s++) {
            int ka = s ? ka1 : ka0;
            s16x8 af[4], bfr[4];
            #pragma unroll
            for (int f = 0; f < 4; f++) {
                af[f]  = *(const s16x8*)&Ac[(arow + f*16)*64 + ka];
                bfr[f] = *(const s16x8*)&Bs[(brow + f*16)*64 + ka];
            }
            __builtin_amdgcn_s_setprio(1);
            #pragma unroll
            for (int mf = 0; mf < 4; mf++)
                #pragma unroll
                for (int nf = 0; nf < 4; nf++)
                    acc[mf][nf] = __builtin_amdgcn_mfma_f32_16x16x32_bf16(af[mf], bfr[nf], acc[mf][nf], 0,0,0);
            __builtin_amdgcn_s_setprio(0);
        }
    }

    #pragma unroll
    for (int mf = 0; mf < 4; mf++) {
        int ib = wr*64 + mf*16 + lq*4;
        #pragma unroll
        for (int nf = 0; nf < 4; nf++) {
            int j = n0 + wc*64 + nf*16 + l15;
            #pragma unroll
            for (int r = 0; r < 4; r++) {
                int i = ib + r;
                float v = acc[mf][nf][r];
                if (!ROUTED) {
                    out[(size_t)(m0+i)*N + j] = v;
                } else {
                    int code = codes[i];
                    if (code >= 0)
                        y[((size_t)(code & 1)*T_TOK + (code >> 1))*N + j] = f2bf(v);
                }
            }
        }
    }
}

// ---- combine ----
__global__ void combine_kernel(float* __restrict__ out, const unsigned short* __restrict__ y) {
    size_t i = (size_t)blockIdx.x * 256 + threadIdx.x;
    s16x8 a = ((const s16x8*)y)[i];
    s16x8 b = ((const s16x8*)(y + (size_t)T_TOK*DMODEL))[i];
    float4 o0 = ((const float4*)out)[i*2];
    float4 o1 = ((const float4*)out)[i*2+1];
    o0.x += bf2f((unsigned short)a[0]) + bf2f((unsigned short)b[0]);
    o0.y += bf2f((unsigned short)a[1]) + bf2f((unsigned short)b[1]);
    o0.z += bf2f((unsigned short)a[2]) + bf2f((unsigned short)b[2]);
    o0.w += bf2f((unsigned short)a[3]) + bf2f((unsigned short)b[3]);
    o1.x += bf2f((unsigned short)a[4]) + bf2f((unsigned short)b[4]);
    o1.y += bf2f((unsigned short)a[5]) + bf2f((unsigned short)b[5]);
    o1.z += bf2f((unsigned short)a[6]) + bf2f((unsigned short)b[6]);
    o1.w += bf2f((unsigned short)a[7]) + bf2f((unsigned short)b[7]);
    ((float4*)out)[i*2]   = o0;
    ((float4*)out)[i*2+1] = o1;
}

extern "C" void kernel_launch(void* const* d_in, const int* in_sizes, int n_in,
                              void* d_out, int out_size, void* d_ws, size_t ws_size,
                              hipStream_t stream) {
    const float* x   = (const float*)d_in[0];
    const float* wg  = (const float*)d_in[1];
    const float* sw1 = (const float*)d_in[2];
    const float* sw3 = (const float*)d_in[3];
    const float* sw2 = (const float*)d_in[4];
    const float* ew1 = (const float*)d_in[5];
    const float* ew3 = (const float*)d_in[6];
    const float* ew2 = (const float*)d_in[7];
    float* out = (float*)d_out;
    char* ws = (char*)d_ws;
    unsigned short* xb  = (unsigned short*)(ws + XB_OFF);
    unsigned short* H   = (unsigned short*)(ws + H_OFF);
    unsigned short* y   = (unsigned short*)(ws + Y_OFF);
    unsigned short* wsh = (unsigned short*)(ws + WSH_OFF);
    char* c = ws + C_OFF;
    int*   cnt    = (int*)  (c + CNT_OFF);
    int*   off    = (int*)  (c + OFF_OFF);
    int*   cur    = (int*)  (c + CUR_OFF);
    int*   tile_e = (int*)  (c + TILEE_OFF);
    int*   tki    = (int*)  (c + TKI_OFF);
    float* tkw    = (float*)(c + TKW_OFF);
    int*   lcode  = (int*)  (c + LCODE_OFF);
    float* lw     = (float*)(c + LW_OFF);
    bool bw = (ws_size >= WS_NEED);

    hipMemsetAsync(cnt, 0, 64, stream);
    cvt_x_kernel<<<8192, 256, 0, stream>>>(x, xb);
    gate_kernel<<<T_TOK, 256, 0, stream>>>(x, wg, tki, tkw, cnt);
    scan_kernel<<<1, 256, 0, stream>>>(cnt, off, cur, tile_e, lcode);
    fill_kernel<<<16, 256, 0, stream>>>(tki, tkw, off, cur, lcode, lw);
    if (bw) {
        wcvt_sh_kernel<<<12288, 256, 0, stream>>>(sw1, sw3, sw2, wsh);
        gemm1_kernel<false, true><<<dim3(ISH/128, T_TOK/128), 256, 0, stream>>>(
            xb, wsh, wsh + WELEM, H, ISH, nullptr, nullptr, nullptr);
        gemm2_kernel<false, true><<<dim3(DMODEL/128, T_TOK/128), 256, 0, stream>>>(
            H, wsh + 2*WELEM, out, nullptr, ISH, nullptr, nullptr);
    } else {
        gemm1_kernel<false, false><<<dim3(ISH/128, T_TOK/128), 256, 0, stream>>>(
            xb, sw1, sw3, H, ISH, nullptr, nullptr, nullptr);
        gemm2_kernel<false, false><<<dim3(DMODEL/128, T_TOK/128), 256, 0, stream>>>(
            H, sw2, out, nullptr, ISH, nullptr, nullptr);
    }
    gemm1_kernel<true, false><<<dim3(IMOE/128, MAXTILES), 256, 0, stream>>>(
        xb, ew1, ew3, H, IMOE, lcode, lw, tile_e);
    gemm2_kernel<true, false><<<dim3(DMODEL/128, MAXTILES), 256, 0, stream>>>(
        H, ew2, nullptr, y, IMOE, lcode, tile_e);
    combine_kernel<<<4096, 256, 0, stream>>>(out, y);
}

// Round 13
// 871.538 us; speedup vs baseline: 1.2746x; 1.2746x over previous
//
#include <hip/hip_runtime.h>
#include <hip/hip_bf16.h>

typedef __attribute__((ext_vector_type(8))) short s16x8;
typedef __attribute__((ext_vector_type(4))) short s16x4;
typedef __attribute__((ext_vector_type(4))) float f32x4;

#define T_TOK 4096
#define DMODEL 2048
#define ISH 4096
#define IMOE 2048
#define NEXP 16
#define MAXTILES 80
#define PADMAX (MAXTILES*128)     // 10240
#define WELEM ((size_t)ISH*DMODEL) // elems per shared weight matrix

// ---- workspace layout (bytes) ----
#define XB_OFF   ((size_t)0)                              // 16,777,216
#define H_OFF    ((size_t)16777216)
#define H_BYTES  ((size_t)PADMAX*IMOE*2)                  // 41,943,040
#define Y_OFF    (H_OFF + H_BYTES)                        // 58,720,256
#define Y_BYTES  ((size_t)2*T_TOK*DMODEL*2)               // 33,554,432
#define C_OFF    (Y_OFF + Y_BYTES)                        // 92,274,688
#define WSH_OFF  (C_OFF + (size_t)1048576)                // 93,323,264
#define WSH_BYTES ((size_t)3*WELEM*2)                     // 50,331,648
#define WS_NEED  (WSH_OFF + WSH_BYTES)                    // ~143.7 MB
// control block offsets (bytes from C_OFF)
#define CNT_OFF    0
#define OFF_OFF    64
#define CUR_OFF    192
#define TILEE_OFF  256
#define TKI_OFF    1024
#define TKW_OFF    (TKI_OFF + T_TOK*2*4)
#define LCODE_OFF  (TKW_OFF + T_TOK*2*4)
#define LW_OFF     (LCODE_OFF + PADMAX*4)

__device__ __forceinline__ unsigned short f2bf(float f) {
    union { float f; unsigned u; } c; c.f = f;
    unsigned u = c.u;
    u += 0x7fffu + ((u >> 16) & 1u);   // RNE
    return (unsigned short)(u >> 16);
}
__device__ __forceinline__ float bf2f(unsigned short h) {
    union { unsigned u; float f; } c; c.u = ((unsigned)h) << 16; return c.f;
}

__device__ __forceinline__ s16x8 cvt8(float4 a, float4 b) {
    union { __hip_bfloat162 h2[4]; s16x8 v; } u;
    u.h2[0] = __float22bfloat162_rn(make_float2(a.x, a.y));
    u.h2[1] = __float22bfloat162_rn(make_float2(a.z, a.w));
    u.h2[2] = __float22bfloat162_rn(make_float2(b.x, b.y));
    u.h2[3] = __float22bfloat162_rn(make_float2(b.z, b.w));
    return u.v;
}

__device__ __forceinline__ void gl_lds16(const unsigned short* g, unsigned short* l) {
    __builtin_amdgcn_global_load_lds(
        (const __attribute__((address_space(1))) unsigned int*)g,
        (__attribute__((address_space(3))) unsigned int*)l,
        16, 0, 0);
}

// ---- cast x (fp32) -> xb (bf16) ----
__global__ void cvt_x_kernel(const float* __restrict__ x, unsigned short* __restrict__ xb) {
    size_t i = (size_t)blockIdx.x * 256 + threadIdx.x;
    float4 v = ((const float4*)x)[i];
    s16x4 o;
    o[0] = (short)f2bf(v.x); o[1] = (short)f2bf(v.y);
    o[2] = (short)f2bf(v.z); o[3] = (short)f2bf(v.w);
    ((s16x4*)xb)[i] = o;
}

// ---- shared weights fp32 -> bf16 (w1 | w3 | w2 contiguous) ----
__global__ void wcvt_sh_kernel(const float* __restrict__ a, const float* __restrict__ b,
                               const float* __restrict__ c, unsigned short* __restrict__ o) {
    size_t i = (size_t)blockIdx.x * 256 + threadIdx.x;   // chunk of 8 elems
    size_t w = i >> 20;
    size_t idx = (i & ((((size_t)1) << 20) - 1)) << 3;
    const float* src = (w == 0) ? a : (w == 1) ? b : c;
    float4 x = *(const float4*)(src + idx);
    float4 y = *(const float4*)(src + idx + 4);
    *(s16x8*)(o + (i << 3)) = cvt8(x, y);
}

// ---- gate ----
__global__ void gate_kernel(const float* __restrict__ x, const float* __restrict__ wg,
                            int* __restrict__ tki, float* __restrict__ tkw, int* __restrict__ cnt) {
    int t = blockIdx.x;
    __shared__ float xs[DMODEL];
    __shared__ float lg[NEXP];
    const float* xr = x + (size_t)t * DMODEL;
    for (int i = threadIdx.x; i < DMODEL; i += 256) xs[i] = xr[i];
    __syncthreads();
    int g = threadIdx.x >> 4, l = threadIdx.x & 15;
    const float* w = wg + (size_t)g * DMODEL;
    double s = 0.0;
    for (int i = l; i < DMODEL; i += 16) s += (double)xs[i] * (double)w[i];
    for (int m = 8; m >= 1; m >>= 1) s += __shfl_xor(s, m, 64);
    if (l == 0) lg[g] = (float)s;
    __syncthreads();
    if (threadIdx.x == 0) {
        float v0 = -1e30f, v1 = -1e30f; int i0 = 0, i1 = 0;
        for (int e = 0; e < NEXP; e++) {
            float v = lg[e];
            if (v > v0) { v1 = v0; i1 = i0; v0 = v; i0 = e; }
            else if (v > v1) { v1 = v; i1 = e; }
        }
        float w0 = 1.f / (1.f + expf(v1 - v0));
        float w1 = 1.f - w0;
        tki[t*2] = i0; tki[t*2+1] = i1;
        tkw[t*2] = w0; tkw[t*2+1] = w1;
        atomicAdd(&cnt[i0], 1); atomicAdd(&cnt[i1], 1);
    }
}

// ---- scan: 128-aligned segments ----
__global__ void scan_kernel(const int* __restrict__ cnt, int* __restrict__ off,
                            int* __restrict__ cur, int* __restrict__ tile_e,
                            int* __restrict__ lcode) {
    __shared__ int soff[17];
    if (threadIdx.x == 0) {
        int o = 0;
        for (int e = 0; e < NEXP; e++) {
            soff[e] = o; off[e] = o; cur[e] = 0;
            o += (cnt[e] + 127) & ~127;
        }
        soff[16] = o; off[16] = o;
    }
    __syncthreads();
    int ntiles = soff[16] >> 7;
    for (int i = threadIdx.x; i < MAXTILES; i += 256) {
        int e = -1;
        if (i < ntiles) {
            for (int j = 0; j < NEXP; j++)
                if (i*128 >= soff[j] && i*128 < soff[j+1]) e = j;
        }
        tile_e[i] = e;
    }
    for (int p = threadIdx.x; p < PADMAX; p += 256) lcode[p] = -1;
}

__global__ void fill_kernel(const int* __restrict__ tki, const float* __restrict__ tkw,
                            const int* __restrict__ off, int* __restrict__ cur,
                            int* __restrict__ lcode, float* __restrict__ lw) {
    int t = blockIdx.x * 256 + threadIdx.x;
    if (t >= T_TOK) return;
    for (int k = 0; k < 2; k++) {
        int e = tki[t*2+k];
        int p = atomicAdd(&cur[e], 1);
        int pos = off[e] + p;
        lcode[pos] = t*2 + k;
        lw[pos] = tkw[t*2+k];
    }
}

// ===================================================================
// r8 skeleton (best measured: 880 us): BM=BN=128, BK=64, 256 thr /
// 4 waves (2x2), wave tile 64x64, SINGLE LDS buffer. A always bf16
// via global_load_lds (linear dest, pre-swizzled src). BF16W: B same
// (prefetch t+1 after compute). !BF16W: B fp32 staged IN-LOOP (m97
// pattern). Swizzle: byte ^= ((row&7)<<4) in 128B rows; conflicts 0.
// Round-13 change: gemm2 gets __launch_bounds__(256,3) (single-acc
// skeleton proven lean at 3 waves/SIMD in r11; LDS 32.5KB allows 3
// blocks/CU). gemm1 keeps (256,2) (dual acc = 128 AGPR can't fit 3).
// ===================================================================

// ---- GEMM1: H = silu(A@W1^T) * (A@W3^T) * wt ----
template<bool ROUTED, bool BF16W>
__global__ __launch_bounds__(256, 2)
void gemm1_kernel(const unsigned short* __restrict__ xb,
                  const void* __restrict__ w1v, const void* __restrict__ w3v,
                  unsigned short* __restrict__ H, const int N,
                  const int* __restrict__ list_code, const float* __restrict__ list_w,
                  const int* __restrict__ tile_e) {
    const int K = DMODEL;
    const int NT = K / 64;
    int gx = gridDim.x, gy = gridDim.y;
    int wg0 = blockIdx.y * gx + blockIdx.x;
    int cpx = (gx * gy) >> 3;
    int sw = (wg0 & 7) * cpx + (wg0 >> 3);
    int mt = sw % gy, nt = sw / gy;
    const float *w1 = nullptr, *w3 = nullptr;
    const unsigned short *w1h = nullptr, *w3h = nullptr;
    if constexpr (BF16W) { w1h = (const unsigned short*)w1v; w3h = (const unsigned short*)w3v; }
    else                 { w1  = (const float*)w1v;          w3  = (const float*)w3v; }
    if (ROUTED) {
        int e = tile_e[mt];
        if (e < 0) return;
        size_t es = (size_t)N * K;
        if constexpr (BF16W) { w1h += (size_t)e * es; w3h += (size_t)e * es; }
        else                 { w1  += (size_t)e * es; w3  += (size_t)e * es; }
    }
    int m0 = mt*128, n0 = nt*128;

    __shared__ alignas(16) unsigned short Ab [128*64];   // 16 KB
    __shared__ alignas(16) unsigned short B1s[128*64];   // 16 KB
    __shared__ alignas(16) unsigned short B3s[128*64];   // 16 KB
    __shared__ int   toks[128];
    __shared__ float wts[128];

    int tid = threadIdx.x;
    if (tid < 128) {
        if (ROUTED) {
            int code = list_code[m0 + tid];
            toks[tid] = (code < 0) ? 0 : (code >> 1);
            wts[tid]  = (code < 0) ? 0.f : list_w[m0 + tid];
        } else {
            toks[tid] = m0 + tid; wts[tid] = 1.f;
        }
    }
    __syncthreads();

    // A staging: 4 x gl_lds (1024 chunks / 256 thr)
    const unsigned short* aSrc[4];
    int aDst[4];
    #pragma unroll
    for (int r = 0; r < 4; r++) {
        int c = r*256 + tid, row = c >> 3;
        int kb = ((c & 7) * 16) ^ ((row & 7) << 4);
        aSrc[r] = xb + (size_t)toks[row] * K + (kb >> 1);
        aDst[r] = c * 8;
    }
    // B staging geometry: 4 chunks/thread per matrix (full 1024 coverage)
    const unsigned short *b1g[4], *b3g[4];
    const float *b1f32[4], *b3f32[4];
    int bW[4];
    if constexpr (BF16W) {
        #pragma unroll
        for (int r = 0; r < 4; r++) {
            int c = r*256 + tid, row = c >> 3;
            int kb = ((c & 7) * 16) ^ ((row & 7) << 4);
            b1g[r] = w1h + (size_t)(n0 + row) * K + (kb >> 1);
            b3g[r] = w3h + (size_t)(n0 + row) * K + (kb >> 1);
        }
    } else {
        #pragma unroll
        for (int p = 0; p < 4; p++) {
            int c = p*256 + tid, row = c >> 3, slot = c & 7;
            b1f32[p] = w1 + (size_t)(n0 + row) * K + slot*8;
            b3f32[p] = w3 + (size_t)(n0 + row) * K + slot*8;
            bW[p] = row*64 + ((slot ^ (row & 7)) << 3);
        }
    }

    int wid = tid >> 6, lane = tid & 63;
    int wr = wid >> 1, wc = wid & 1;
    int l15 = lane & 15, lq = lane >> 4, lx = (lane & 7) << 4;
    int arow = wr*64 + l15, brow = wc*64 + l15;
    int ka0 = ((lq*16) ^ lx) >> 1;
    int ka1 = ((64 + lq*16) ^ lx) >> 1;

    f32x4 acc1[4][4], acc2[4][4];
    #pragma unroll
    for (int a = 0; a < 4; a++)
        #pragma unroll
        for (int b = 0; b < 4; b++) {
            acc1[a][b] = (f32x4){0.f,0.f,0.f,0.f};
            acc2[a][b] = (f32x4){0.f,0.f,0.f,0.f};
        }

    if constexpr (BF16W) {
        // prologue: stage tile 0 (12 gl_lds)
        #pragma unroll
        for (int r = 0; r < 4; r++) gl_lds16(aSrc[r], &Ab[aDst[r]]);
        #pragma unroll
        for (int r = 0; r < 4; r++) { gl_lds16(b1g[r], &B1s[aDst[r]]); gl_lds16(b3g[r], &B3s[aDst[r]]); }
    }

    for (int t = 0; t < NT; ++t) {
        int kt = t * 64, kn = kt + 64;
        bool pre = (t + 1 < NT);
        if constexpr (!BF16W) {
            __syncthreads();                 // readers of tile t-1 done; LDS free
            #pragma unroll
            for (int r = 0; r < 4; r++) gl_lds16(aSrc[r] + kt, &Ab[aDst[r]]);
            #pragma unroll
            for (int p = 0; p < 4; p++) {
                float4 a1 = *(const float4*)(b1f32[p] + kt);
                float4 b1 = *(const float4*)(b1f32[p] + kt + 4);
                float4 a3 = *(const float4*)(b3f32[p] + kt);
                float4 b3 = *(const float4*)(b3f32[p] + kt + 4);
                *(s16x8*)&B1s[bW[p]] = cvt8(a1, b1);
                *(s16x8*)&B3s[bW[p]] = cvt8(a3, b3);
            }
        }
        __syncthreads();                     // drains gl_lds (vmcnt0) + ds_writes
        // ---- compute tile t ----
        #pragma unroll
        for (int s = 0; s < 2; s++) {
            int ka = s ? ka1 : ka0;
            s16x8 af[4], b1fr[4], b3fr[4];
            #pragma unroll
            for (int f = 0; f < 4; f++) {
                af[f]   = *(const s16x8*)&Ab [(arow + f*16)*64 + ka];
                b1fr[f] = *(const s16x8*)&B1s[(brow + f*16)*64 + ka];
                b3fr[f] = *(const s16x8*)&B3s[(brow + f*16)*64 + ka];
            }
            __builtin_amdgcn_s_setprio(1);
            #pragma unroll
            for (int mf = 0; mf < 4; mf++)
                #pragma unroll
                for (int nf = 0; nf < 4; nf++) {
                    acc1[mf][nf] = __builtin_amdgcn_mfma_f32_16x16x32_bf16(af[mf], b1fr[nf], acc1[mf][nf], 0,0,0);
                    acc2[mf][nf] = __builtin_amdgcn_mfma_f32_16x16x32_bf16(af[mf], b3fr[nf], acc2[mf][nf], 0,0,0);
                }
            __builtin_amdgcn_s_setprio(0);
        }
        if constexpr (BF16W) {
            __syncthreads();                 // all lanes done reading tile t
            if (pre) {
                #pragma unroll
                for (int r = 0; r < 4; r++) gl_lds16(aSrc[r] + kn, &Ab[aDst[r]]);
                #pragma unroll
                for (int r = 0; r < 4; r++) { gl_lds16(b1g[r] + kn, &B1s[aDst[r]]); gl_lds16(b3g[r] + kn, &B3s[aDst[r]]); }
            }
        }
    }

    // ---- epilogue ----
    #pragma unroll
    for (int mf = 0; mf < 4; mf++) {
        int ib = wr*64 + mf*16 + lq*4;
        #pragma unroll
        for (int nf = 0; nf < 4; nf++) {
            int j = n0 + wc*64 + nf*16 + l15;
            #pragma unroll
            for (int r = 0; r < 4; r++) {
                int i = ib + r;
                float v1 = acc1[mf][nf][r], v2 = acc2[mf][nf][r];
                float sg = v1 / (1.f + __expf(-v1));
                float h = sg * v2 * wts[i];
                H[(size_t)(m0+i)*N + j] = f2bf(h);
            }
        }
    }
}

// ---- GEMM2: Y = H @ W2^T ----
template<bool ROUTED, bool BF16W>
__global__ __launch_bounds__(256, 3)
void gemm2_kernel(const unsigned short* __restrict__ Hm, const void* __restrict__ w2v,
                  float* __restrict__ out, unsigned short* __restrict__ y, const int K,
                  const int* __restrict__ list_code, const int* __restrict__ tile_e) {
    const int N = DMODEL;
    const int NT = K / 64;
    int gx = gridDim.x, gy = gridDim.y;
    int wg0 = blockIdx.y * gx + blockIdx.x;
    int cpx = (gx * gy) >> 3;
    int sw = (wg0 & 7) * cpx + (wg0 >> 3);
    int mt = sw % gy, nt = sw / gy;
    const float* w2 = nullptr; const unsigned short* w2h = nullptr;
    if constexpr (BF16W) w2h = (const unsigned short*)w2v; else w2 = (const float*)w2v;
    if (ROUTED) {
        int e = tile_e[mt];
        if (e < 0) return;
        if constexpr (BF16W) w2h += (size_t)e * N * K; else w2 += (size_t)e * N * K;
    }
    int m0 = mt*128, n0 = nt*128;

    __shared__ alignas(16) unsigned short Ab[128*64];
    __shared__ alignas(16) unsigned short Bs[128*64];
    __shared__ int codes[128];
    int tid = threadIdx.x;
    if (ROUTED && tid < 128) codes[tid] = list_code[m0 + tid];
    if (ROUTED) __syncthreads();

    const unsigned short* aSrc[4];
    int aDst[4];
    #pragma unroll
    for (int r = 0; r < 4; r++) {
        int c = r*256 + tid, row = c >> 3;
        int kb = ((c & 7) * 16) ^ ((row & 7) << 4);
        aSrc[r] = Hm + (size_t)(m0 + row) * K + (kb >> 1);
        aDst[r] = c * 8;
    }
    const unsigned short* bg[4];
    const float* bf32[4];
    int bW[4];
    if constexpr (BF16W) {
        #pragma unroll
        for (int r = 0; r < 4; r++) {
            int c = r*256 + tid, row = c >> 3;
            int kb = ((c & 7) * 16) ^ ((row & 7) << 4);
            bg[r] = w2h + (size_t)(n0 + row) * K + (kb >> 1);
        }
    } else {
        #pragma unroll
        for (int p = 0; p < 4; p++) {
            int c = p*256 + tid, r = c >> 3, slot = c & 7;
            bf32[p] = w2 + (size_t)(n0 + r) * K + slot*8;
            bW[p] = r*64 + ((slot ^ (r & 7)) << 3);
        }
    }

    int wid = tid >> 6, lane = tid & 63;
    int wr = wid >> 1, wc = wid & 1;
    int l15 = lane & 15, lq = lane >> 4, lx = (lane & 7) << 4;
    int arow = wr*64 + l15, brow = wc*64 + l15;
    int ka0 = ((lq*16) ^ lx) >> 1;
    int ka1 = ((64 + lq*16) ^ lx) >> 1;

    f32x4 acc[4][4];
    #pragma unroll
    for (int a = 0; a < 4; a++)
        #pragma unroll
        for (int b = 0; b < 4; b++) acc[a][b] = (f32x4){0.f,0.f,0.f,0.f};

    if constexpr (BF16W) {
        #pragma unroll
        for (int r = 0; r < 4; r++) { gl_lds16(aSrc[r], &Ab[aDst[r]]); gl_lds16(bg[r], &Bs[aDst[r]]); }
    }

    for (int t = 0; t < NT; ++t) {
        int kt = t * 64, kn = kt + 64;
        bool pre = (t + 1 < NT);
        if constexpr (!BF16W) {
            __syncthreads();
            #pragma unroll
            for (int r = 0; r < 4; r++) gl_lds16(aSrc[r] + kt, &Ab[aDst[r]]);
            #pragma unroll
            for (int p = 0; p < 4; p++) {
                float4 a0 = *(const float4*)(bf32[p] + kt);
                float4 b0 = *(const float4*)(bf32[p] + kt + 4);
                *(s16x8*)&Bs[bW[p]] = cvt8(a0, b0);
            }
        }
        __syncthreads();
        #pragma unroll
        for (int s = 0; s < 2; s++) {
            int ka = s ? ka1 : ka0;
            s16x8 af[4], bfr[4];
            #pragma unroll
            for (int f = 0; f < 4; f++) {
                af[f]  = *(const s16x8*)&Ab[(arow + f*16)*64 + ka];
                bfr[f] = *(const s16x8*)&Bs[(brow + f*16)*64 + ka];
            }
            __builtin_amdgcn_s_setprio(1);
            #pragma unroll
            for (int mf = 0; mf < 4; mf++)
                #pragma unroll
                for (int nf = 0; nf < 4; nf++)
                    acc[mf][nf] = __builtin_amdgcn_mfma_f32_16x16x32_bf16(af[mf], bfr[nf], acc[mf][nf], 0,0,0);
            __builtin_amdgcn_s_setprio(0);
        }
        if constexpr (BF16W) {
            __syncthreads();
            if (pre) {
                #pragma unroll
                for (int r = 0; r < 4; r++) { gl_lds16(aSrc[r] + kn, &Ab[aDst[r]]); gl_lds16(bg[r] + kn, &Bs[aDst[r]]); }
            }
        }
    }

    #pragma unroll
    for (int mf = 0; mf < 4; mf++) {
        int ib = wr*64 + mf*16 + lq*4;
        #pragma unroll
        for (int nf = 0; nf < 4; nf++) {
            int j = n0 + wc*64 + nf*16 + l15;
            #pragma unroll
            for (int r = 0; r < 4; r++) {
                int i = ib + r;
                float v = acc[mf][nf][r];
                if (!ROUTED) {
                    out[(size_t)(m0+i)*N + j] = v;
                } else {
                    int code = codes[i];
                    if (code >= 0)
                        y[((size_t)(code & 1)*T_TOK + (code >> 1))*N + j] = f2bf(v);
                }
            }
        }
    }
}

// ---- combine ----
__global__ void combine_kernel(float* __restrict__ out, const unsigned short* __restrict__ y) {
    size_t i = (size_t)blockIdx.x * 256 + threadIdx.x;
    s16x8 a = ((const s16x8*)y)[i];
    s16x8 b = ((const s16x8*)(y + (size_t)T_TOK*DMODEL))[i];
    float4 o0 = ((const float4*)out)[i*2];
    float4 o1 = ((const float4*)out)[i*2+1];
    o0.x += bf2f((unsigned short)a[0]) + bf2f((unsigned short)b[0]);
    o0.y += bf2f((unsigned short)a[1]) + bf2f((unsigned short)b[1]);
    o0.z += bf2f((unsigned short)a[2]) + bf2f((unsigned short)b[2]);
    o0.w += bf2f((unsigned short)a[3]) + bf2f((unsigned short)b[3]);
    o1.x += bf2f((unsigned short)a[4]) + bf2f((unsigned short)b[4]);
    o1.y += bf2f((unsigned short)a[5]) + bf2f((unsigned short)b[5]);
    o1.z += bf2f((unsigned short)a[6]) + bf2f((unsigned short)b[6]);
    o1.w += bf2f((unsigned short)a[7]) + bf2f((unsigned short)b[7]);
    ((float4*)out)[i*2]   = o0;
    ((float4*)out)[i*2+1] = o1;
}

extern "C" void kernel_launch(void* const* d_in, const int* in_sizes, int n_in,
                              void* d_out, int out_size, void* d_ws, size_t ws_size,
                              hipStream_t stream) {
    const float* x   = (const float*)d_in[0];
    const float* wg  = (const float*)d_in[1];
    const float* sw1 = (const float*)d_in[2];
    const float* sw3 = (const float*)d_in[3];
    const float* sw2 = (const float*)d_in[4];
    const float* ew1 = (const float*)d_in[5];
    const float* ew3 = (const float*)d_in[6];
    const float* ew2 = (const float*)d_in[7];
    float* out = (float*)d_out;
    char* ws = (char*)d_ws;
    unsigned short* xb  = (unsigned short*)(ws + XB_OFF);
    unsigned short* H   = (unsigned short*)(ws + H_OFF);
    unsigned short* y   = (unsigned short*)(ws + Y_OFF);
    unsigned short* wsh = (unsigned short*)(ws + WSH_OFF);
    char* c = ws + C_OFF;
    int*   cnt    = (int*)  (c + CNT_OFF);
    int*   off    = (int*)  (c + OFF_OFF);
    int*   cur    = (int*)  (c + CUR_OFF);
    int*   tile_e = (int*)  (c + TILEE_OFF);
    int*   tki    = (int*)  (c + TKI_OFF);
    float* tkw    = (float*)(c + TKW_OFF);
    int*   lcode  = (int*)  (c + LCODE_OFF);
    float* lw     = (float*)(c + LW_OFF);
    bool bw = (ws_size >= WS_NEED);

    hipMemsetAsync(cnt, 0, 64, stream);
    cvt_x_kernel<<<8192, 256, 0, stream>>>(x, xb);
    gate_kernel<<<T_TOK, 256, 0, stream>>>(x, wg, tki, tkw, cnt);
    scan_kernel<<<1, 256, 0, stream>>>(cnt, off, cur, tile_e, lcode);
    fill_kernel<<<16, 256, 0, stream>>>(tki, tkw, off, cur, lcode, lw);
    if (bw) {
        wcvt_sh_kernel<<<12288, 256, 0, stream>>>(sw1, sw3, sw2, wsh);
        gemm1_kernel<false, true><<<dim3(ISH/128, T_TOK/128), 256, 0, stream>>>(
            xb, wsh, wsh + WELEM, H, ISH, nullptr, nullptr, nullptr);
        gemm2_kernel<false, true><<<dim3(DMODEL/128, T_TOK/128), 256, 0, stream>>>(
            H, wsh + 2*WELEM, out, nullptr, ISH, nullptr, nullptr);
    } else {
        gemm1_kernel<false, false><<<dim3(ISH/128, T_TOK/128), 256, 0, stream>>>(
            xb, sw1, sw3, H, ISH, nullptr, nullptr, nullptr);
        gemm2_kernel<false, false><<<dim3(DMODEL/128, T_TOK/128), 256, 0, stream>>>(
            H, sw2, out, nullptr, ISH, nullptr, nullptr);
    }
    gemm1_kernel<true, false><<<dim3(IMOE/128, MAXTILES), 256, 0, stream>>>(
        xb, ew1, ew3, H, IMOE, lcode, lw, tile_e);
    gemm2_kernel<true, false><<<dim3(DMODEL/128, MAXTILES), 256, 0, stream>>>(
        H, ew2, nullptr, y, IMOE, lcode, tile_e);
    combine_kernel<<<4096, 256, 0, stream>>>(out, y);
}

// Round 14
// 858.307 us; speedup vs baseline: 1.2942x; 1.0154x over previous
//
#include <hip/hip_runtime.h>
#include <hip/hip_bf16.h>

typedef __attribute__((ext_vector_type(8))) short s16x8;
typedef __attribute__((ext_vector_type(4))) short s16x4;
typedef __attribute__((ext_vector_type(4))) float f32x4;

#define T_TOK 4096
#define DMODEL 2048
#define ISH 4096
#define IMOE 2048
#define NEXP 16
#define MAXTILES 80
#define PADMAX (MAXTILES*128)     // 10240
#define WELEM ((size_t)ISH*DMODEL) // elems per shared weight matrix

// ---- workspace layout (bytes) ----
#define XB_OFF   ((size_t)0)                              // 16,777,216
#define H_OFF    ((size_t)16777216)
#define H_BYTES  ((size_t)PADMAX*IMOE*2)                  // 41,943,040
#define Y_OFF    (H_OFF + H_BYTES)                        // 58,720,256
#define Y_BYTES  ((size_t)2*T_TOK*DMODEL*2)               // 33,554,432
#define C_OFF    (Y_OFF + Y_BYTES)                        // 92,274,688
#define WSH_OFF  (C_OFF + (size_t)1048576)                // 93,323,264
#define WSH_BYTES ((size_t)3*WELEM*2)                     // 50,331,648
#define WS_NEED  (WSH_OFF + WSH_BYTES)                    // ~143.7 MB
// control block offsets (bytes from C_OFF)
#define CNT_OFF    0
#define OFF_OFF    64
#define CUR_OFF    192
#define TILEE_OFF  256
#define TKI_OFF    1024
#define TKW_OFF    (TKI_OFF + T_TOK*2*4)
#define LCODE_OFF  (TKW_OFF + T_TOK*2*4)
#define LW_OFF     (LCODE_OFF + PADMAX*4)

__device__ __forceinline__ unsigned short f2bf(float f) {
    union { float f; unsigned u; } c; c.f = f;
    unsigned u = c.u;
    u += 0x7fffu + ((u >> 16) & 1u);   // RNE
    return (unsigned short)(u >> 16);
}
__device__ __forceinline__ float bf2f(unsigned short h) {
    union { unsigned u; float f; } c; c.u = ((unsigned)h) << 16; return c.f;
}

__device__ __forceinline__ s16x8 cvt8(float4 a, float4 b) {
    union { __hip_bfloat162 h2[4]; s16x8 v; } u;
    u.h2[0] = __float22bfloat162_rn(make_float2(a.x, a.y));
    u.h2[1] = __float22bfloat162_rn(make_float2(a.z, a.w));
    u.h2[2] = __float22bfloat162_rn(make_float2(b.x, b.y));
    u.h2[3] = __float22bfloat162_rn(make_float2(b.z, b.w));
    return u.v;
}

__device__ __forceinline__ void gl_lds16(const unsigned short* g, unsigned short* l) {
    __builtin_amdgcn_global_load_lds(
        (const __attribute__((address_space(1))) unsigned int*)g,
        (__attribute__((address_space(3))) unsigned int*)l,
        16, 0, 0);
}

// ---- shared weights fp32 -> bf16 (w1 | w3 | w2 contiguous) ----
__global__ void wcvt_sh_kernel(const float* __restrict__ a, const float* __restrict__ b,
                               const float* __restrict__ c, unsigned short* __restrict__ o) {
    size_t i = (size_t)blockIdx.x * 256 + threadIdx.x;   // chunk of 8 elems
    size_t w = i >> 20;
    size_t idx = (i & ((((size_t)1) << 20) - 1)) << 3;
    const float* src = (w == 0) ? a : (w == 1) ? b : c;
    float4 x = *(const float4*)(src + idx);
    float4 y = *(const float4*)(src + idx + 4);
    *(s16x8*)(o + (i << 3)) = cvt8(x, y);
}

// ---- gate (fused: also emits bf16 x row) ----
__global__ void gate_kernel(const float* __restrict__ x, const float* __restrict__ wg,
                            unsigned short* __restrict__ xb,
                            int* __restrict__ tki, float* __restrict__ tkw, int* __restrict__ cnt) {
    int t = blockIdx.x;
    __shared__ float xs[DMODEL];
    __shared__ float lg[NEXP];
    const float* xr = x + (size_t)t * DMODEL;
    for (int i = threadIdx.x; i < DMODEL; i += 256) xs[i] = xr[i];
    __syncthreads();
    // emit bf16 row from LDS copy (8 elems/thread, one 16B store)
    {
        int i0 = threadIdx.x * 8;
        float4 a = *(const float4*)&xs[i0];
        float4 b = *(const float4*)&xs[i0 + 4];
        *(s16x8*)&xb[(size_t)t * DMODEL + i0] = cvt8(a, b);
    }
    int g = threadIdx.x >> 4, l = threadIdx.x & 15;
    const float* w = wg + (size_t)g * DMODEL;
    double s = 0.0;
    for (int i = l; i < DMODEL; i += 16) s += (double)xs[i] * (double)w[i];
    for (int m = 8; m >= 1; m >>= 1) s += __shfl_xor(s, m, 64);
    if (l == 0) lg[g] = (float)s;
    __syncthreads();
    if (threadIdx.x == 0) {
        float v0 = -1e30f, v1 = -1e30f; int i0 = 0, i1 = 0;
        for (int e = 0; e < NEXP; e++) {
            float v = lg[e];
            if (v > v0) { v1 = v0; i1 = i0; v0 = v; i0 = e; }
            else if (v > v1) { v1 = v; i1 = e; }
        }
        float w0 = 1.f / (1.f + expf(v1 - v0));
        float w1 = 1.f - w0;
        tki[t*2] = i0; tki[t*2+1] = i1;
        tkw[t*2] = w0; tkw[t*2+1] = w1;
        atomicAdd(&cnt[i0], 1); atomicAdd(&cnt[i1], 1);
    }
}

// ---- scan: 128-aligned segments ----
__global__ void scan_kernel(const int* __restrict__ cnt, int* __restrict__ off,
                            int* __restrict__ cur, int* __restrict__ tile_e,
                            int* __restrict__ lcode) {
    __shared__ int soff[17];
    if (threadIdx.x == 0) {
        int o = 0;
        for (int e = 0; e < NEXP; e++) {
            soff[e] = o; off[e] = o; cur[e] = 0;
            o += (cnt[e] + 127) & ~127;
        }
        soff[16] = o; off[16] = o;
    }
    __syncthreads();
    int ntiles = soff[16] >> 7;
    for (int i = threadIdx.x; i < MAXTILES; i += 256) {
        int e = -1;
        if (i < ntiles) {
            for (int j = 0; j < NEXP; j++)
                if (i*128 >= soff[j] && i*128 < soff[j+1]) e = j;
        }
        tile_e[i] = e;
    }
    for (int p = threadIdx.x; p < PADMAX; p += 256) lcode[p] = -1;
}

__global__ void fill_kernel(const int* __restrict__ tki, const float* __restrict__ tkw,
                            const int* __restrict__ off, int* __restrict__ cur,
                            int* __restrict__ lcode, float* __restrict__ lw) {
    int t = blockIdx.x * 256 + threadIdx.x;
    if (t >= T_TOK) return;
    for (int k = 0; k < 2; k++) {
        int e = tki[t*2+k];
        int p = atomicAdd(&cur[e], 1);
        int pos = off[e] + p;
        lcode[pos] = t*2 + k;
        lw[pos] = tkw[t*2+k];
    }
}

// ===================================================================
// r13 skeleton (best measured: 871.5 us): BM=BN=128, BK=64, 256 thr /
// 4 waves (2x2), wave tile 64x64, SINGLE LDS buffer. A always bf16
// via global_load_lds (linear dest, pre-swizzled src). BF16W: B same
// (prefetch t+1 after compute). !BF16W: B fp32 staged IN-LOOP (m97
// pattern). Swizzle: byte ^= ((row&7)<<4) in 128B rows; conflicts 0.
// gemm2: __launch_bounds__(256,3) (single-acc, 3 blocks/CU — r13 win).
// gemm1 keeps (256,2) (dual acc = 128 AGPR can't fit 3 waves/SIMD).
// ===================================================================

// ---- GEMM1: H = silu(A@W1^T) * (A@W3^T) * wt ----
template<bool ROUTED, bool BF16W>
__global__ __launch_bounds__(256, 2)
void gemm1_kernel(const unsigned short* __restrict__ xb,
                  const void* __restrict__ w1v, const void* __restrict__ w3v,
                  unsigned short* __restrict__ H, const int N,
                  const int* __restrict__ list_code, const float* __restrict__ list_w,
                  const int* __restrict__ tile_e) {
    const int K = DMODEL;
    const int NT = K / 64;
    int gx = gridDim.x, gy = gridDim.y;
    int wg0 = blockIdx.y * gx + blockIdx.x;
    int cpx = (gx * gy) >> 3;
    int sw = (wg0 & 7) * cpx + (wg0 >> 3);
    int mt = sw % gy, nt = sw / gy;
    const float *w1 = nullptr, *w3 = nullptr;
    const unsigned short *w1h = nullptr, *w3h = nullptr;
    if constexpr (BF16W) { w1h = (const unsigned short*)w1v; w3h = (const unsigned short*)w3v; }
    else                 { w1  = (const float*)w1v;          w3  = (const float*)w3v; }
    if (ROUTED) {
        int e = tile_e[mt];
        if (e < 0) return;
        size_t es = (size_t)N * K;
        if constexpr (BF16W) { w1h += (size_t)e * es; w3h += (size_t)e * es; }
        else                 { w1  += (size_t)e * es; w3  += (size_t)e * es; }
    }
    int m0 = mt*128, n0 = nt*128;

    __shared__ alignas(16) unsigned short Ab [128*64];   // 16 KB
    __shared__ alignas(16) unsigned short B1s[128*64];   // 16 KB
    __shared__ alignas(16) unsigned short B3s[128*64];   // 16 KB
    __shared__ int   toks[128];
    __shared__ float wts[128];

    int tid = threadIdx.x;
    if (tid < 128) {
        if (ROUTED) {
            int code = list_code[m0 + tid];
            toks[tid] = (code < 0) ? 0 : (code >> 1);
            wts[tid]  = (code < 0) ? 0.f : list_w[m0 + tid];
        } else {
            toks[tid] = m0 + tid; wts[tid] = 1.f;
        }
    }
    __syncthreads();

    // A staging: 4 x gl_lds (1024 chunks / 256 thr)
    const unsigned short* aSrc[4];
    int aDst[4];
    #pragma unroll
    for (int r = 0; r < 4; r++) {
        int c = r*256 + tid, row = c >> 3;
        int kb = ((c & 7) * 16) ^ ((row & 7) << 4);
        aSrc[r] = xb + (size_t)toks[row] * K + (kb >> 1);
        aDst[r] = c * 8;
    }
    // B staging geometry: 4 chunks/thread per matrix (full 1024 coverage)
    const unsigned short *b1g[4], *b3g[4];
    const float *b1f32[4], *b3f32[4];
    int bW[4];
    if constexpr (BF16W) {
        #pragma unroll
        for (int r = 0; r < 4; r++) {
            int c = r*256 + tid, row = c >> 3;
            int kb = ((c & 7) * 16) ^ ((row & 7) << 4);
            b1g[r] = w1h + (size_t)(n0 + row) * K + (kb >> 1);
            b3g[r] = w3h + (size_t)(n0 + row) * K + (kb >> 1);
        }
    } else {
        #pragma unroll
        for (int p = 0; p < 4; p++) {
            int c = p*256 + tid, row = c >> 3, slot = c & 7;
            b1f32[p] = w1 + (size_t)(n0 + row) * K + slot*8;
            b3f32[p] = w3 + (size_t)(n0 + row) * K + slot*8;
            bW[p] = row*64 + ((slot ^ (row & 7)) << 3);
        }
    }

    int wid = tid >> 6, lane = tid & 63;
    int wr = wid >> 1, wc = wid & 1;
    int l15 = lane & 15, lq = lane >> 4, lx = (lane & 7) << 4;
    int arow = wr*64 + l15, brow = wc*64 + l15;
    int ka0 = ((lq*16) ^ lx) >> 1;
    int ka1 = ((64 + lq*16) ^ lx) >> 1;

    f32x4 acc1[4][4], acc2[4][4];
    #pragma unroll
    for (int a = 0; a < 4; a++)
        #pragma unroll
        for (int b = 0; b < 4; b++) {
            acc1[a][b] = (f32x4){0.f,0.f,0.f,0.f};
            acc2[a][b] = (f32x4){0.f,0.f,0.f,0.f};
        }

    if constexpr (BF16W) {
        // prologue: stage tile 0 (12 gl_lds)
        #pragma unroll
        for (int r = 0; r < 4; r++) gl_lds16(aSrc[r], &Ab[aDst[r]]);
        #pragma unroll
        for (int r = 0; r < 4; r++) { gl_lds16(b1g[r], &B1s[aDst[r]]); gl_lds16(b3g[r], &B3s[aDst[r]]); }
    }

    for (int t = 0; t < NT; ++t) {
        int kt = t * 64, kn = kt + 64;
        bool pre = (t + 1 < NT);
        if constexpr (!BF16W) {
            __syncthreads();                 // readers of tile t-1 done; LDS free
            #pragma unroll
            for (int r = 0; r < 4; r++) gl_lds16(aSrc[r] + kt, &Ab[aDst[r]]);
            #pragma unroll
            for (int p = 0; p < 4; p++) {
                float4 a1 = *(const float4*)(b1f32[p] + kt);
                float4 b1 = *(const float4*)(b1f32[p] + kt + 4);
                float4 a3 = *(const float4*)(b3f32[p] + kt);
                float4 b3 = *(const float4*)(b3f32[p] + kt + 4);
                *(s16x8*)&B1s[bW[p]] = cvt8(a1, b1);
                *(s16x8*)&B3s[bW[p]] = cvt8(a3, b3);
            }
        }
        __syncthreads();                     // drains gl_lds (vmcnt0) + ds_writes
        // ---- compute tile t ----
        #pragma unroll
        for (int s = 0; s < 2; s++) {
            int ka = s ? ka1 : ka0;
            s16x8 af[4], b1fr[4], b3fr[4];
            #pragma unroll
            for (int f = 0; f < 4; f++) {
                af[f]   = *(const s16x8*)&Ab [(arow + f*16)*64 + ka];
                b1fr[f] = *(const s16x8*)&B1s[(brow + f*16)*64 + ka];
                b3fr[f] = *(const s16x8*)&B3s[(brow + f*16)*64 + ka];
            }
            __builtin_amdgcn_s_setprio(1);
            #pragma unroll
            for (int mf = 0; mf < 4; mf++)
                #pragma unroll
                for (int nf = 0; nf < 4; nf++) {
                    acc1[mf][nf] = __builtin_amdgcn_mfma_f32_16x16x32_bf16(af[mf], b1fr[nf], acc1[mf][nf], 0,0,0);
                    acc2[mf][nf] = __builtin_amdgcn_mfma_f32_16x16x32_bf16(af[mf], b3fr[nf], acc2[mf][nf], 0,0,0);
                }
            __builtin_amdgcn_s_setprio(0);
        }
        if constexpr (BF16W) {
            __syncthreads();                 // all lanes done reading tile t
            if (pre) {
                #pragma unroll
                for (int r = 0; r < 4; r++) gl_lds16(aSrc[r] + kn, &Ab[aDst[r]]);
                #pragma unroll
                for (int r = 0; r < 4; r++) { gl_lds16(b1g[r] + kn, &B1s[aDst[r]]); gl_lds16(b3g[r] + kn, &B3s[aDst[r]]); }
            }
        }
    }

    // ---- epilogue ----
    #pragma unroll
    for (int mf = 0; mf < 4; mf++) {
        int ib = wr*64 + mf*16 + lq*4;
        #pragma unroll
        for (int nf = 0; nf < 4; nf++) {
            int j = n0 + wc*64 + nf*16 + l15;
            #pragma unroll
            for (int r = 0; r < 4; r++) {
                int i = ib + r;
                float v1 = acc1[mf][nf][r], v2 = acc2[mf][nf][r];
                float sg = v1 / (1.f + __expf(-v1));
                float h = sg * v2 * wts[i];
                H[(size_t)(m0+i)*N + j] = f2bf(h);
            }
        }
    }
}

// ---- GEMM2: Y = H @ W2^T ----
template<bool ROUTED, bool BF16W>
__global__ __launch_bounds__(256, 3)
void gemm2_kernel(const unsigned short* __restrict__ Hm, const void* __restrict__ w2v,
                  float* __restrict__ out, unsigned short* __restrict__ y, const int K,
                  const int* __restrict__ list_code, const int* __restrict__ tile_e) {
    const int N = DMODEL;
    const int NT = K / 64;
    int gx = gridDim.x, gy = gridDim.y;
    int wg0 = blockIdx.y * gx + blockIdx.x;
    int cpx = (gx * gy) >> 3;
    int sw = (wg0 & 7) * cpx + (wg0 >> 3);
    int mt = sw % gy, nt = sw / gy;
    const float* w2 = nullptr; const unsigned short* w2h = nullptr;
    if constexpr (BF16W) w2h = (const unsigned short*)w2v; else w2 = (const float*)w2v;
    if (ROUTED) {
        int e = tile_e[mt];
        if (e < 0) return;
        if constexpr (BF16W) w2h += (size_t)e * N * K; else w2 += (size_t)e * N * K;
    }
    int m0 = mt*128, n0 = nt*128;

    __shared__ alignas(16) unsigned short Ab[128*64];
    __shared__ alignas(16) unsigned short Bs[128*64];
    __shared__ int codes[128];
    int tid = threadIdx.x;
    if (ROUTED && tid < 128) codes[tid] = list_code[m0 + tid];
    if (ROUTED) __syncthreads();

    const unsigned short* aSrc[4];
    int aDst[4];
    #pragma unroll
    for (int r = 0; r < 4; r++) {
        int c = r*256 + tid, row = c >> 3;
        int kb = ((c & 7) * 16) ^ ((row & 7) << 4);
        aSrc[r] = Hm + (size_t)(m0 + row) * K + (kb >> 1);
        aDst[r] = c * 8;
    }
    const unsigned short* bg[4];
    const float* bf32[4];
    int bW[4];
    if constexpr (BF16W) {
        #pragma unroll
        for (int r = 0; r < 4; r++) {
            int c = r*256 + tid, row = c >> 3;
            int kb = ((c & 7) * 16) ^ ((row & 7) << 4);
            bg[r] = w2h + (size_t)(n0 + row) * K + (kb >> 1);
        }
    } else {
        #pragma unroll
        for (int p = 0; p < 4; p++) {
            int c = p*256 + tid, r = c >> 3, slot = c & 7;
            bf32[p] = w2 + (size_t)(n0 + r) * K + slot*8;
            bW[p] = r*64 + ((slot ^ (r & 7)) << 3);
        }
    }

    int wid = tid >> 6, lane = tid & 63;
    int wr = wid >> 1, wc = wid & 1;
    int l15 = lane & 15, lq = lane >> 4, lx = (lane & 7) << 4;
    int arow = wr*64 + l15, brow = wc*64 + l15;
    int ka0 = ((lq*16) ^ lx) >> 1;
    int ka1 = ((64 + lq*16) ^ lx) >> 1;

    f32x4 acc[4][4];
    #pragma unroll
    for (int a = 0; a < 4; a++)
        #pragma unroll
        for (int b = 0; b < 4; b++) acc[a][b] = (f32x4){0.f,0.f,0.f,0.f};

    if constexpr (BF16W) {
        #pragma unroll
        for (int r = 0; r < 4; r++) { gl_lds16(aSrc[r], &Ab[aDst[r]]); gl_lds16(bg[r], &Bs[aDst[r]]); }
    }

    for (int t = 0; t < NT; ++t) {
        int kt = t * 64, kn = kt + 64;
        bool pre = (t + 1 < NT);
        if constexpr (!BF16W) {
            __syncthreads();
            #pragma unroll
            for (int r = 0; r < 4; r++) gl_lds16(aSrc[r] + kt, &Ab[aDst[r]]);
            #pragma unroll
            for (int p = 0; p < 4; p++) {
                float4 a0 = *(const float4*)(bf32[p] + kt);
                float4 b0 = *(const float4*)(bf32[p] + kt + 4);
                *(s16x8*)&Bs[bW[p]] = cvt8(a0, b0);
            }
        }
        __syncthreads();
        #pragma unroll
        for (int s = 0; s < 2; s++) {
            int ka = s ? ka1 : ka0;
            s16x8 af[4], bfr[4];
            #pragma unroll
            for (int f = 0; f < 4; f++) {
                af[f]  = *(const s16x8*)&Ab[(arow + f*16)*64 + ka];
                bfr[f] = *(const s16x8*)&Bs[(brow + f*16)*64 + ka];
            }
            __builtin_amdgcn_s_setprio(1);
            #pragma unroll
            for (int mf = 0; mf < 4; mf++)
                #pragma unroll
                for (int nf = 0; nf < 4; nf++)
                    acc[mf][nf] = __builtin_amdgcn_mfma_f32_16x16x32_bf16(af[mf], bfr[nf], acc[mf][nf], 0,0,0);
            __builtin_amdgcn_s_setprio(0);
        }
        if constexpr (BF16W) {
            __syncthreads();
            if (pre) {
                #pragma unroll
                for (int r = 0; r < 4; r++) { gl_lds16(aSrc[r] + kn, &Ab[aDst[r]]); gl_lds16(bg[r] + kn, &Bs[aDst[r]]); }
            }
        }
    }

    #pragma unroll
    for (int mf = 0; mf < 4; mf++) {
        int ib = wr*64 + mf*16 + lq*4;
        #pragma unroll
        for (int nf = 0; nf < 4; nf++) {
            int j = n0 + wc*64 + nf*16 + l15;
            #pragma unroll
            for (int r = 0; r < 4; r++) {
                int i = ib + r;
                float v = acc[mf][nf][r];
                if (!ROUTED) {
                    out[(size_t)(m0+i)*N + j] = v;
                } else {
                    int code = codes[i];
                    if (code >= 0)
                        y[((size_t)(code & 1)*T_TOK + (code >> 1))*N + j] = f2bf(v);
                }
            }
        }
    }
}

// ---- combine ----
__global__ void combine_kernel(float* __restrict__ out, const unsigned short* __restrict__ y) {
    size_t i = (size_t)blockIdx.x * 256 + threadIdx.x;
    s16x8 a = ((const s16x8*)y)[i];
    s16x8 b = ((const s16x8*)(y + (size_t)T_TOK*DMODEL))[i];
    float4 o0 = ((const float4*)out)[i*2];
    float4 o1 = ((const float4*)out)[i*2+1];
    o0.x += bf2f((unsigned short)a[0]) + bf2f((unsigned short)b[0]);
    o0.y += bf2f((unsigned short)a[1]) + bf2f((unsigned short)b[1]);
    o0.z += bf2f((unsigned short)a[2]) + bf2f((unsigned short)b[2]);
    o0.w += bf2f((unsigned short)a[3]) + bf2f((unsigned short)b[3]);
    o1.x += bf2f((unsigned short)a[4]) + bf2f((unsigned short)b[4]);
    o1.y += bf2f((unsigned short)a[5]) + bf2f((unsigned short)b[5]);
    o1.z += bf2f((unsigned short)a[6]) + bf2f((unsigned short)b[6]);
    o1.w += bf2f((unsigned short)a[7]) + bf2f((unsigned short)b[7]);
    ((float4*)out)[i*2]   = o0;
    ((float4*)out)[i*2+1] = o1;
}

extern "C" void kernel_launch(void* const* d_in, const int* in_sizes, int n_in,
                              void* d_out, int out_size, void* d_ws, size_t ws_size,
                              hipStream_t stream) {
    const float* x   = (const float*)d_in[0];
    const float* wg  = (const float*)d_in[1];
    const float* sw1 = (const float*)d_in[2];
    const float* sw3 = (const float*)d_in[3];
    const float* sw2 = (const float*)d_in[4];
    const float* ew1 = (const float*)d_in[5];
    const float* ew3 = (const float*)d_in[6];
    const float* ew2 = (const float*)d_in[7];
    float* out = (float*)d_out;
    char* ws = (char*)d_ws;
    unsigned short* xb  = (unsigned short*)(ws + XB_OFF);
    unsigned short* H   = (unsigned short*)(ws + H_OFF);
    unsigned short* y   = (unsigned short*)(ws + Y_OFF);
    unsigned short* wsh = (unsigned short*)(ws + WSH_OFF);
    char* c = ws + C_OFF;
    int*   cnt    = (int*)  (c + CNT_OFF);
    int*   off    = (int*)  (c + OFF_OFF);
    int*   cur    = (int*)  (c + CUR_OFF);
    int*   tile_e = (int*)  (c + TILEE_OFF);
    int*   tki    = (int*)  (c + TKI_OFF);
    float* tkw    = (float*)(c + TKW_OFF);
    int*   lcode  = (int*)  (c + LCODE_OFF);
    float* lw     = (float*)(c + LW_OFF);
    bool bw = (ws_size >= WS_NEED);

    hipMemsetAsync(cnt, 0, 64, stream);
    gate_kernel<<<T_TOK, 256, 0, stream>>>(x, wg, xb, tki, tkw, cnt);
    scan_kernel<<<1, 256, 0, stream>>>(cnt, off, cur, tile_e, lcode);
    fill_kernel<<<16, 256, 0, stream>>>(tki, tkw, off, cur, lcode, lw);
    if (bw) {
        wcvt_sh_kernel<<<12288, 256, 0, stream>>>(sw1, sw3, sw2, wsh);
        gemm1_kernel<false, true><<<dim3(ISH/128, T_TOK/128), 256, 0, stream>>>(
            xb, wsh, wsh + WELEM, H, ISH, nullptr, nullptr, nullptr);
        gemm2_kernel<false, true><<<dim3(DMODEL/128, T_TOK/128), 256, 0, stream>>>(
            H, wsh + 2*WELEM, out, nullptr, ISH, nullptr, nullptr);
    } else {
        gemm1_kernel<false, false><<<dim3(ISH/128, T_TOK/128), 256, 0, stream>>>(
            xb, sw1, sw3, H, ISH, nullptr, nullptr, nullptr);
        gemm2_kernel<false, false><<<dim3(DMODEL/128, T_TOK/128), 256, 0, stream>>>(
            H, sw2, out, nullptr, ISH, nullptr, nullptr);
    }
    gemm1_kernel<true, false><<<dim3(IMOE/128, MAXTILES), 256, 0, stream>>>(
        xb, ew1, ew3, H, IMOE, lcode, lw, tile_e);
    gemm2_kernel<true, false><<<dim3(DMODEL/128, MAXTILES), 256, 0, stream>>>(
        H, ew2, nullptr, y, IMOE, lcode, tile_e);
    combine_kernel<<<4096, 256, 0, stream>>>(out, y);
}